// Round 1
// baseline (261.349 us; speedup 1.0000x reference)
//
#include <hip/hip_runtime.h>

// EdgePredictor: score = sigmoid(sum(h[src] * h[dst])) for two edge sets.
// h: [100000, 128] fp32; edges_[ab]: [2, 1M] int (int64 per reference, but
// JAX may have demoted to int32 -- detected at runtime, see detect kernel).
// out: score_a [0..1M) ++ score_b [1M..2M), fp32.

#define N_NODES 100000
#define D_FEAT  128
#define N_EDGES 1000000

// One thread decides whether the edge arrays are int64 or int32.
// Reads the first 8 values interpreted as int64: genuine int64 indices are
// all in [0, N_NODES); int32 data reinterpreted as int64 gives values
// >= 2^32 unless the adjacent index is exactly 0 (prob ~1e-5 each).
__global__ void detect_idx_dtype(const void* __restrict__ edges_a,
                                 int* __restrict__ flag) {
    if (blockIdx.x == 0 && threadIdx.x == 0) {
        const long long* p = (const long long*)edges_a;
        int is64 = 1;
        for (int i = 0; i < 8; ++i) {
            long long v = p[i];
            if (v < 0 || v >= N_NODES) { is64 = 0; break; }
        }
        *flag = is64;
    }
}

// 16 lanes cooperate per edge: each lane loads 2 float4 (32B) of the src row
// and dst row (512B per row per 16-lane group, fully coalesced), partial dot,
// then 4-step shfl_xor reduction within the 16-lane group.
__global__ __launch_bounds__(256) void edge_pred_kernel(
    const float* __restrict__ h,
    const void* __restrict__ ea,
    const void* __restrict__ eb,
    float* __restrict__ out,
    const int* __restrict__ flag)
{
    int gid  = blockIdx.x * 256 + threadIdx.x;
    int edge = gid >> 4;        // global edge id in [0, 2M)
    int lane = gid & 15;
    if (edge >= 2 * N_EDGES) return;

    const int is64 = *flag;     // uniform; L1-broadcast load

    const void* edges = (edge < N_EDGES) ? ea : eb;
    int e = (edge < N_EDGES) ? edge : edge - N_EDGES;

    long long src, dst;
    if (is64) {
        const long long* ep = (const long long*)edges;
        src = ep[e];
        dst = ep[e + N_EDGES];
    } else {
        const int* ep = (const int*)edges;
        src = (long long)ep[e];
        dst = (long long)ep[e + N_EDGES];
    }

    const float4* ps = (const float4*)(h + src * D_FEAT) + lane * 2;
    const float4* pd = (const float4*)(h + dst * D_FEAT) + lane * 2;
    float4 s0 = ps[0];
    float4 s1 = ps[1];
    float4 d0 = pd[0];
    float4 d1 = pd[1];

    float acc = s0.x * d0.x + s0.y * d0.y + s0.z * d0.z + s0.w * d0.w
              + s1.x * d1.x + s1.y * d1.y + s1.z * d1.z + s1.w * d1.w;

    // reduce across the 16-lane group (offsets 1,2,4,8 stay within group)
    #pragma unroll
    for (int off = 8; off >= 1; off >>= 1)
        acc += __shfl_xor(acc, off, 64);

    if (lane == 0)
        out[edge] = 1.0f / (1.0f + expf(-acc));
}

extern "C" void kernel_launch(void* const* d_in, const int* in_sizes, int n_in,
                              void* d_out, int out_size, void* d_ws, size_t ws_size,
                              hipStream_t stream) {
    const float* h  = (const float*)d_in[0];
    const void*  ea = d_in[1];
    const void*  eb = d_in[2];
    float* out = (float*)d_out;
    int* flag = (int*)d_ws;

    detect_idx_dtype<<<1, 64, 0, stream>>>(ea, flag);

    const long long total_threads = (long long)2 * N_EDGES * 16;  // 32M
    const int block = 256;
    const int grid = (int)((total_threads + block - 1) / block);  // 125000
    edge_pred_kernel<<<grid, block, 0, stream>>>(h, ea, eb, out, flag);
}

// Round 2
// 193.986 us; speedup vs baseline: 1.3473x; 1.3473x over previous
//
#include <hip/hip_runtime.h>
#include <hip/hip_fp16.h>

// EdgePredictor: score = sigmoid(sum(h[src] * h[dst])) for two edge sets.
// Strategy: per-call convert h (fp32 [100000,128], 51.2MB) to fp16 in d_ws
// (25.6MB) -- halves the random-gather traffic which bounds this kernel
// (R1: 2.05GB gathered in 256us ~ 8TB/s L2/L3 traffic, VALU 28%).
// Then 16 lanes/edge gather 16B each of src+dst fp16 rows, dot, sigmoid.

#define N_NODES 100000
#define D_FEAT  128
#define N_EDGES 1000000

#define H16_BYTES ((size_t)N_NODES * D_FEAT * 2)   // 25,600,000
#define FLAG_OFF  0
#define H16_OFF   64

// One thread decides whether the edge arrays are int64 or int32.
__global__ void detect_idx_dtype(const void* __restrict__ edges_a,
                                 int* __restrict__ flag) {
    if (blockIdx.x == 0 && threadIdx.x == 0) {
        const long long* p = (const long long*)edges_a;
        int is64 = 1;
        for (int i = 0; i < 8; ++i) {
            long long v = p[i];
            if (v < 0 || v >= N_NODES) { is64 = 0; break; }
        }
        *flag = is64;
    }
}

// fp32 -> fp16 conversion, 8 elems/thread (32B in, 16B out).
// 12.8M elems -> 1.6M threads.
__global__ __launch_bounds__(256) void convert_h_fp16(
    const float* __restrict__ h, __half* __restrict__ hh) {
    int i = blockIdx.x * 256 + threadIdx.x;
    const int total = N_NODES * D_FEAT / 8;  // 1,600,000
    if (i >= total) return;
    const float4* src = (const float4*)h;
    float4 a = src[2 * i];
    float4 b = src[2 * i + 1];
    __half2 r[4];
    r[0] = __float22half2_rn(make_float2(a.x, a.y));
    r[1] = __float22half2_rn(make_float2(a.z, a.w));
    r[2] = __float22half2_rn(make_float2(b.x, b.y));
    r[3] = __float22half2_rn(make_float2(b.z, b.w));
    ((float4*)hh)[i] = *(const float4*)r;
}

__device__ __forceinline__ float dot8_f16(float4 sv, float4 dv, float acc) {
    const __half2* s2 = (const __half2*)&sv;
    const __half2* d2 = (const __half2*)&dv;
#if __has_builtin(__builtin_amdgcn_fdot2)
    #pragma unroll
    for (int j = 0; j < 4; ++j)
        acc = __builtin_amdgcn_fdot2(s2[j], d2[j], acc, false);
#else
    #pragma unroll
    for (int j = 0; j < 4; ++j) {
        float2 sf = __half22float2(s2[j]);
        float2 df = __half22float2(d2[j]);
        acc += sf.x * df.x + sf.y * df.y;
    }
#endif
    return acc;
}

// 16 lanes/edge; each lane loads one float4 (16B = 8 halves) of src row and
// dst row (256B per row per group, fully coalesced), then shfl_xor reduce.
__global__ __launch_bounds__(256) void edge_pred_fp16(
    const __half* __restrict__ hh,
    const void* __restrict__ ea,
    const void* __restrict__ eb,
    float* __restrict__ out,
    const int* __restrict__ flag)
{
    int gid  = blockIdx.x * 256 + threadIdx.x;
    int edge = gid >> 4;
    int lane = gid & 15;
    if (edge >= 2 * N_EDGES) return;

    const int is64 = *flag;

    const void* edges = (edge < N_EDGES) ? ea : eb;
    int e = (edge < N_EDGES) ? edge : edge - N_EDGES;

    long long src, dst;
    if (is64) {
        const long long* ep = (const long long*)edges;
        src = ep[e];
        dst = ep[e + N_EDGES];
    } else {
        const int* ep = (const int*)edges;
        src = (long long)ep[e];
        dst = (long long)ep[e + N_EDGES];
    }

    const float4* ps = (const float4*)(hh + src * D_FEAT) + lane;
    const float4* pd = (const float4*)(hh + dst * D_FEAT) + lane;
    float4 sv = *ps;
    float4 dv = *pd;

    float acc = dot8_f16(sv, dv, 0.0f);

    #pragma unroll
    for (int off = 8; off >= 1; off >>= 1)
        acc += __shfl_xor(acc, off, 64);

    if (lane == 0)
        out[edge] = 1.0f / (1.0f + expf(-acc));
}

// ---- fallback fp32 path (used only if ws_size too small) ----
__global__ __launch_bounds__(256) void edge_pred_fp32(
    const float* __restrict__ h,
    const void* __restrict__ ea,
    const void* __restrict__ eb,
    float* __restrict__ out,
    const int* __restrict__ flag)
{
    int gid  = blockIdx.x * 256 + threadIdx.x;
    int edge = gid >> 4;
    int lane = gid & 15;
    if (edge >= 2 * N_EDGES) return;

    const int is64 = *flag;
    const void* edges = (edge < N_EDGES) ? ea : eb;
    int e = (edge < N_EDGES) ? edge : edge - N_EDGES;

    long long src, dst;
    if (is64) {
        const long long* ep = (const long long*)edges;
        src = ep[e];
        dst = ep[e + N_EDGES];
    } else {
        const int* ep = (const int*)edges;
        src = (long long)ep[e];
        dst = (long long)ep[e + N_EDGES];
    }

    const float4* ps = (const float4*)(h + src * D_FEAT) + lane * 2;
    const float4* pd = (const float4*)(h + dst * D_FEAT) + lane * 2;
    float4 s0 = ps[0], s1 = ps[1], d0 = pd[0], d1 = pd[1];

    float acc = s0.x * d0.x + s0.y * d0.y + s0.z * d0.z + s0.w * d0.w
              + s1.x * d1.x + s1.y * d1.y + s1.z * d1.z + s1.w * d1.w;

    #pragma unroll
    for (int off = 8; off >= 1; off >>= 1)
        acc += __shfl_xor(acc, off, 64);

    if (lane == 0)
        out[edge] = 1.0f / (1.0f + expf(-acc));
}

extern "C" void kernel_launch(void* const* d_in, const int* in_sizes, int n_in,
                              void* d_out, int out_size, void* d_ws, size_t ws_size,
                              hipStream_t stream) {
    const float* h  = (const float*)d_in[0];
    const void*  ea = d_in[1];
    const void*  eb = d_in[2];
    float* out = (float*)d_out;
    int* flag = (int*)((char*)d_ws + FLAG_OFF);

    detect_idx_dtype<<<1, 64, 0, stream>>>(ea, flag);

    const long long total_threads = (long long)2 * N_EDGES * 16;  // 32M
    const int block = 256;
    const int grid = (int)((total_threads + block - 1) / block);  // 125000

    if (ws_size >= H16_OFF + H16_BYTES) {
        __half* hh = (__half*)((char*)d_ws + H16_OFF);
        const int conv_total = N_NODES * D_FEAT / 8;              // 1.6M
        convert_h_fp16<<<(conv_total + block - 1) / block, block, 0, stream>>>(h, hh);
        edge_pred_fp16<<<grid, block, 0, stream>>>(hh, ea, eb, out, flag);
    } else {
        edge_pred_fp32<<<grid, block, 0, stream>>>(h, ea, eb, out, flag);
    }
}